// Round 1
// baseline (385.052 us; speedup 1.0000x reference)
//
#include <hip/hip_runtime.h>
#include <hip/hip_bf16.h>

#define T_SEQ 4096
#define DMODEL 1024
#define NHEADS 16
#define HDIM 64
#define QBLK 64
#define SBLK 64
#define KSTRIDE 72   // 64 + 8 pad: 144B row stride -> 2-way bank alias max (free)

typedef __attribute__((ext_vector_type(8))) __bf16 bf16x8;
typedef __attribute__((ext_vector_type(4))) __bf16 bf16x4;
typedef __attribute__((ext_vector_type(4))) float f32x4;

// One block = one head x one 64-row Q tile. 4 waves, each owns 16 Q rows.
// K/V are the same tensor as Q (q=k=v=x), so stage the x-tile once from
// global, write it to LDS in both [s][d] (K) and [d][s] (V^T) layouts.
__global__ __launch_bounds__(256) void attn_fused_kernel(
    const float* __restrict__ x, float* __restrict__ out) {
  const int tid  = threadIdx.x;
  const int wave = tid >> 6;
  const int lane = tid & 63;
  const int lr   = lane & 15;   // MFMA "row/col" lane index
  const int lg   = lane >> 4;   // MFMA k-group / row-group

  const int qt = blockIdx.x & 63;   // Q tile index
  const int h  = blockIdx.x >> 6;   // head

  __shared__ __bf16 Kl[SBLK][KSTRIDE];     // K tile [s][d]
  __shared__ __bf16 Vt[HDIM][KSTRIDE];     // V tile transposed [d][s]
  __shared__ __bf16 Pl[4][16][KSTRIDE];    // per-wave P round-trip [16 rows][64 s]

  // ---- load Q fragments into registers, scale 1/8 folded in (exact pow2) ----
  bf16x8 qf[2];
  {
    const int qrow = qt * QBLK + wave * 16 + lr;
    const float* qp = x + (size_t)qrow * DMODEL + h * HDIM;
    #pragma unroll
    for (int kk = 0; kk < 2; kk++) {
      float4 a = *reinterpret_cast<const float4*>(qp + kk * 32 + lg * 8);
      float4 b = *reinterpret_cast<const float4*>(qp + kk * 32 + lg * 8 + 4);
      bf16x8 f;
      f[0] = (__bf16)(0.125f * a.x); f[1] = (__bf16)(0.125f * a.y);
      f[2] = (__bf16)(0.125f * a.z); f[3] = (__bf16)(0.125f * a.w);
      f[4] = (__bf16)(0.125f * b.x); f[5] = (__bf16)(0.125f * b.y);
      f[6] = (__bf16)(0.125f * b.z); f[7] = (__bf16)(0.125f * b.w);
      qf[kk] = f;
    }
  }

  float m_run[4], l_run[4];
  f32x4 o_acc[4];
  const f32x4 vzero = {0.f, 0.f, 0.f, 0.f};
  #pragma unroll
  for (int r = 0; r < 4; r++) { m_run[r] = -1e30f; l_run[r] = 0.f; }
  #pragma unroll
  for (int ct = 0; ct < 4; ct++) o_acc[ct] = vzero;

  const float* xh = x + h * HDIM;

  for (int t0 = 0; t0 < T_SEQ; t0 += SBLK) {
    __syncthreads();   // protect K/Vt from previous iteration's readers
    // ---- stage tile: 64 rows x 64 cols f32 -> bf16, K and V^T layouts ----
    {
      const int c4 = tid & 15;           // float4 column
      #pragma unroll
      for (int i = 0; i < 4; i++) {
        const int s = (tid >> 4) + (i << 4);
        float4 v4 = *reinterpret_cast<const float4*>(
            xh + (size_t)(t0 + s) * DMODEL + c4 * 4);
        __bf16 b0 = (__bf16)v4.x, b1 = (__bf16)v4.y;
        __bf16 b2 = (__bf16)v4.z, b3 = (__bf16)v4.w;
        bf16x4 kv; kv[0] = b0; kv[1] = b1; kv[2] = b2; kv[3] = b3;
        *reinterpret_cast<bf16x4*>(&Kl[s][c4 * 4]) = kv;
        const int d0 = c4 * 4;
        Vt[d0 + 0][s] = b0; Vt[d0 + 1][s] = b1;
        Vt[d0 + 2][s] = b2; Vt[d0 + 3][s] = b3;
      }
    }
    __syncthreads();

    // ---- S = (Q/8) K^T : 16x64 per wave via 8 MFMAs ----
    f32x4 s_acc[4];
    #pragma unroll
    for (int ct = 0; ct < 4; ct++) s_acc[ct] = vzero;
    #pragma unroll
    for (int kk = 0; kk < 2; kk++) {
      #pragma unroll
      for (int ct = 0; ct < 4; ct++) {
        bf16x8 kb = *reinterpret_cast<const bf16x8*>(
            &Kl[ct * 16 + lr][kk * 32 + lg * 8]);
        s_acc[ct] = __builtin_amdgcn_mfma_f32_16x16x32_bf16(
            qf[kk], kb, s_acc[ct], 0, 0, 0);
      }
    }

    // ---- online softmax: 4 rows per lane, 16-lane shfl_xor reductions ----
    #pragma unroll
    for (int r = 0; r < 4; r++) {
      float mx = fmaxf(fmaxf(s_acc[0][r], s_acc[1][r]),
                       fmaxf(s_acc[2][r], s_acc[3][r]));
      #pragma unroll
      for (int off = 8; off > 0; off >>= 1) mx = fmaxf(mx, __shfl_xor(mx, off));
      const float mn   = fmaxf(m_run[r], mx);
      const float corr = __expf(m_run[r] - mn);
      m_run[r] = mn;
      float rs = 0.f;
      #pragma unroll
      for (int ct = 0; ct < 4; ct++) {
        float p = __expf(s_acc[ct][r] - mn);
        rs += p;
        Pl[wave][lg * 4 + r][ct * 16 + lr] = (__bf16)p;
      }
      #pragma unroll
      for (int off = 8; off > 0; off >>= 1) rs += __shfl_xor(rs, off);
      l_run[r] = l_run[r] * corr + rs;
      #pragma unroll
      for (int ct = 0; ct < 4; ct++) o_acc[ct][r] *= corr;
    }

    // ---- O += P V : A-frag from per-wave LDS, B-frag from V^T ----
    #pragma unroll
    for (int kk = 0; kk < 2; kk++) {
      bf16x8 pa = *reinterpret_cast<const bf16x8*>(
          &Pl[wave][lr][kk * 32 + lg * 8]);
      #pragma unroll
      for (int ct = 0; ct < 4; ct++) {
        bf16x8 vb = *reinterpret_cast<const bf16x8*>(
            &Vt[ct * 16 + lr][kk * 32 + lg * 8]);
        o_acc[ct] = __builtin_amdgcn_mfma_f32_16x16x32_bf16(
            pa, vb, o_acc[ct], 0, 0, 0);
      }
    }
  }

  // ---- epilogue: normalize and store f32 ----
  #pragma unroll
  for (int r = 0; r < 4; r++) {
    const float inv = 1.f / l_run[r];
    const int row = qt * QBLK + wave * 16 + lg * 4 + r;
    #pragma unroll
    for (int ct = 0; ct < 4; ct++) {
      out[(size_t)row * DMODEL + h * HDIM + ct * 16 + lr] = o_acc[ct][r] * inv;
    }
  }
}

extern "C" void kernel_launch(void* const* d_in, const int* in_sizes, int n_in,
                              void* d_out, int out_size, void* d_ws, size_t ws_size,
                              hipStream_t stream) {
  const float* x = (const float*)d_in[0];
  float* out = (float*)d_out;
  dim3 grid(NHEADS * (T_SEQ / QBLK));   // 1024 blocks
  attn_fused_kernel<<<grid, 256, 0, stream>>>(x, out);
}

// Round 2
// 343.830 us; speedup vs baseline: 1.1199x; 1.1199x over previous
//
#include <hip/hip_runtime.h>
#include <hip/hip_bf16.h>

#define T_SEQ 4096
#define DMODEL 1024
#define NHEADS 16
#define HDIM 64
#define QBLK 128   // Q rows per block: 4 waves x 32 rows
#define SBLK 64    // KV rows per tile

typedef __attribute__((ext_vector_type(8))) __bf16 bf16x8;
typedef __attribute__((ext_vector_type(4))) __bf16 bf16x4;
typedef __attribute__((ext_vector_type(4))) float f32x4;

// XOR swizzle: element (row, col) of a [*][64] bf16 tile stored at
// col ^ ((row&7)<<3). 8-element (16B) granule; row stride 128B (no pad).
// Balances ds_read_b128 across banks (T2 pattern) and staging writes.
#define SWZ(row, col) ((col) ^ (((row) & 7) << 3))

__global__ __launch_bounds__(256) void attn_fused_kernel(
    const float* __restrict__ x, float* __restrict__ out) {
  const int tid  = threadIdx.x;
  const int wave = tid >> 6;
  const int lane = tid & 63;
  const int lr   = lane & 15;   // MFMA lane row/col
  const int lg   = lane >> 4;   // MFMA k-group / row-group

  const int qt = blockIdx.x & 31;   // 32 Q tiles of 128 rows
  const int h  = blockIdx.x >> 5;   // head

  __shared__ __bf16 Kl[SBLK][HDIM];     // K tile [s][d], swizzled on d
  __shared__ __bf16 Vt[HDIM][SBLK];     // V tile transposed [d][s], swizzled on s
  __shared__ __bf16 Pl[4][16][SBLK];    // per-wave P round-trip, swizzled on col

  // ---- Q fragments: 2 row-subtiles x 2 k-slices, scale 1/8 folded (exact) ----
  bf16x8 qf[2][2];
  #pragma unroll
  for (int rt = 0; rt < 2; rt++) {
    const int qrow = qt * QBLK + wave * 32 + rt * 16 + lr;
    const float* qp = x + (size_t)qrow * DMODEL + h * HDIM;
    #pragma unroll
    for (int kk = 0; kk < 2; kk++) {
      float4 a = *reinterpret_cast<const float4*>(qp + kk * 32 + lg * 8);
      float4 b = *reinterpret_cast<const float4*>(qp + kk * 32 + lg * 8 + 4);
      bf16x8 f;
      f[0] = (__bf16)(0.125f * a.x); f[1] = (__bf16)(0.125f * a.y);
      f[2] = (__bf16)(0.125f * a.z); f[3] = (__bf16)(0.125f * a.w);
      f[4] = (__bf16)(0.125f * b.x); f[5] = (__bf16)(0.125f * b.y);
      f[6] = (__bf16)(0.125f * b.z); f[7] = (__bf16)(0.125f * b.w);
      qf[rt][kk] = f;
    }
  }

  float m_run[2][4], l_run[2][4];
  f32x4 o_acc[2][4];
  const f32x4 vzero = {0.f, 0.f, 0.f, 0.f};
  #pragma unroll
  for (int rt = 0; rt < 2; rt++) {
    #pragma unroll
    for (int r = 0; r < 4; r++) { m_run[rt][r] = -1e30f; l_run[rt][r] = 0.f; }
    #pragma unroll
    for (int ct = 0; ct < 4; ct++) o_acc[rt][ct] = vzero;
  }

  const float* xh = x + h * HDIM;
  const int c4 = tid & 15;   // col block (d/4)
  const int s4 = tid >> 4;   // row block (s/4)

  for (int t0 = 0; t0 < T_SEQ; t0 += SBLK) {
    __syncthreads();   // protect Kl/Vt from previous iteration's readers

    // ---- stage: each thread owns one 4x4 block; vectorized writes both ways ----
    {
      const float* src = xh + (size_t)(t0 + s4 * 4) * DMODEL + c4 * 4;
      float4 r0 = *reinterpret_cast<const float4*>(src);
      float4 r1 = *reinterpret_cast<const float4*>(src + DMODEL);
      float4 r2 = *reinterpret_cast<const float4*>(src + 2 * DMODEL);
      float4 r3 = *reinterpret_cast<const float4*>(src + 3 * DMODEL);
      __bf16 b[4][4];
      b[0][0] = (__bf16)r0.x; b[0][1] = (__bf16)r0.y; b[0][2] = (__bf16)r0.z; b[0][3] = (__bf16)r0.w;
      b[1][0] = (__bf16)r1.x; b[1][1] = (__bf16)r1.y; b[1][2] = (__bf16)r1.z; b[1][3] = (__bf16)r1.w;
      b[2][0] = (__bf16)r2.x; b[2][1] = (__bf16)r2.y; b[2][2] = (__bf16)r2.z; b[2][3] = (__bf16)r2.w;
      b[3][0] = (__bf16)r3.x; b[3][1] = (__bf16)r3.y; b[3][2] = (__bf16)r3.z; b[3][3] = (__bf16)r3.w;
      #pragma unroll
      for (int j = 0; j < 4; j++) {          // K rows
        const int s = s4 * 4 + j;
        bf16x4 kv; kv[0] = b[j][0]; kv[1] = b[j][1]; kv[2] = b[j][2]; kv[3] = b[j][3];
        *reinterpret_cast<bf16x4*>(&Kl[s][SWZ(s, c4 * 4)]) = kv;
      }
      #pragma unroll
      for (int i = 0; i < 4; i++) {          // V^T rows (transposed in registers)
        const int d = c4 * 4 + i;
        bf16x4 vv; vv[0] = b[0][i]; vv[1] = b[1][i]; vv[2] = b[2][i]; vv[3] = b[3][i];
        *reinterpret_cast<bf16x4*>(&Vt[d][SWZ(d, s4 * 4)]) = vv;
      }
    }
    __syncthreads();

    #pragma unroll
    for (int rt = 0; rt < 2; rt++) {
      // ---- S = (Q/8) K^T : 16x64 per row-subtile via 8 MFMAs ----
      f32x4 s_acc[4];
      #pragma unroll
      for (int ct = 0; ct < 4; ct++) s_acc[ct] = vzero;
      #pragma unroll
      for (int kk = 0; kk < 2; kk++) {
        #pragma unroll
        for (int ct = 0; ct < 4; ct++) {
          bf16x8 kb = *reinterpret_cast<const bf16x8*>(
              &Kl[ct * 16 + lr][SWZ(lr, kk * 32 + lg * 8)]);
          s_acc[ct] = __builtin_amdgcn_mfma_f32_16x16x32_bf16(
              qf[rt][kk], kb, s_acc[ct], 0, 0, 0);
        }
      }

      // ---- online softmax: 4 rows per lane, 16-lane shfl_xor reductions ----
      #pragma unroll
      for (int r = 0; r < 4; r++) {
        float mx = fmaxf(fmaxf(s_acc[0][r], s_acc[1][r]),
                         fmaxf(s_acc[2][r], s_acc[3][r]));
        #pragma unroll
        for (int off = 8; off > 0; off >>= 1) mx = fmaxf(mx, __shfl_xor(mx, off));
        const float mn   = fmaxf(m_run[rt][r], mx);
        const float corr = __expf(m_run[rt][r] - mn);
        m_run[rt][r] = mn;
        float rs = 0.f;
        const int prow = lg * 4 + r;
        #pragma unroll
        for (int ct = 0; ct < 4; ct++) {
          float p = __expf(s_acc[ct][r] - mn);
          rs += p;
          Pl[wave][prow][SWZ(prow, ct * 16 + lr)] = (__bf16)p;
        }
        #pragma unroll
        for (int off = 8; off > 0; off >>= 1) rs += __shfl_xor(rs, off);
        l_run[rt][r] = l_run[rt][r] * corr + rs;
        #pragma unroll
        for (int ct = 0; ct < 4; ct++) o_acc[rt][ct][r] *= corr;
      }

      // ---- O += P V ----
      #pragma unroll
      for (int kk = 0; kk < 2; kk++) {
        bf16x8 pa = *reinterpret_cast<const bf16x8*>(
            &Pl[wave][lr][SWZ(lr, kk * 32 + lg * 8)]);
        #pragma unroll
        for (int ct = 0; ct < 4; ct++) {
          bf16x8 vb = *reinterpret_cast<const bf16x8*>(
              &Vt[ct * 16 + lr][SWZ(lr, kk * 32 + lg * 8)]);
          o_acc[rt][ct] = __builtin_amdgcn_mfma_f32_16x16x32_bf16(
              pa, vb, o_acc[rt][ct], 0, 0, 0);
        }
      }
    }
  }

  // ---- epilogue: normalize and store f32 ----
  #pragma unroll
  for (int rt = 0; rt < 2; rt++) {
    #pragma unroll
    for (int r = 0; r < 4; r++) {
      const float inv = 1.f / l_run[rt][r];
      const int row = qt * QBLK + wave * 32 + rt * 16 + lg * 4 + r;
      #pragma unroll
      for (int ct = 0; ct < 4; ct++) {
        out[(size_t)row * DMODEL + h * HDIM + ct * 16 + lr] = o_acc[rt][ct][r] * inv;
      }
    }
  }
}

extern "C" void kernel_launch(void* const* d_in, const int* in_sizes, int n_in,
                              void* d_out, int out_size, void* d_ws, size_t ws_size,
                              hipStream_t stream) {
  const float* x = (const float*)d_in[0];
  float* out = (float*)d_out;
  dim3 grid(NHEADS * (T_SEQ / QBLK));   // 512 blocks
  attn_fused_kernel<<<grid, 256, 0, stream>>>(x, out);
}

// Round 5
// 196.548 us; speedup vs baseline: 1.9591x; 1.7493x over previous
//
#include <hip/hip_runtime.h>
#include <hip/hip_bf16.h>

#define T_SEQ 4096
#define DMODEL 1024
#define NHEADS 16
#define HDIM 64
#define QBLK 128   // 4 waves x 32 q-rows
#define SBLK 64    // KV rows per tile

typedef __attribute__((ext_vector_type(8))) __bf16 bf16x8;
typedef __attribute__((ext_vector_type(4))) __bf16 bf16x4;
typedef __attribute__((ext_vector_type(16))) float f32x16;
typedef __attribute__((ext_vector_type(2))) unsigned uint32x2;

// XOR swizzle on the 8-element (16B) granule; row stride 128B.
#define SWZ(row, col) ((col) ^ (((row) & 7) << 3))

// 1/sqrt(64) * log2(e): fold softmax into exp2 domain (v_exp_f32 is 2^x).
#define QSCALE 0.1803368801111204f

__device__ __forceinline__ unsigned cvt_pk_bf16(float lo, float hi) {
  unsigned r;
  asm("v_cvt_pk_bf16_f32 %0, %1, %2" : "=v"(r) : "v"(lo), "v"(hi));
  return r;
}

// v_permlane32_swap_b32 semantics: vdst[32:63] <-> src[0:31].
// The builtin returns {new_vdst, new_src} as a proper two-value result
// (no inline-asm register-coalescing hazard).
__device__ __forceinline__ uint32x2 plswap(unsigned a, unsigned b) {
  return __builtin_amdgcn_permlane32_swap(a, b, false, false);
}

// Symmetric cross-half reductions (correct for every lane under the
// swap semantics: one of r[0]/r[1] is own, the other is partner).
__device__ __forceinline__ float xhalf_max(float v) {
  uint32x2 r = plswap(__float_as_uint(v), __float_as_uint(v));
  return fmaxf(__uint_as_float(r[0]), __uint_as_float(r[1]));
}
__device__ __forceinline__ float xhalf_sum(float v) {
  uint32x2 r = plswap(__float_as_uint(v), __float_as_uint(v));
  return __uint_as_float(r[0]) + __uint_as_float(r[1]);
}

// Swapped-operand flash attention: per wave, S^T = mfma(K, Q) so each lane
// owns one q-row's 32 scores (of 64; partner lane^32 owns the other 32).
// Softmax fully in-register; P reshaped to the PV B-fragment via
// cvt_pk + permlane32_swap (T12 recipe, no LDS round-trip).
__global__ __launch_bounds__(256) void attn_fused_kernel(
    const float* __restrict__ x, float* __restrict__ out) {
  const int tid  = threadIdx.x;
  const int wave = tid >> 6;
  const int lane = tid & 63;
  const int lq   = lane & 31;   // this lane's q-row (and d-row for PV A-frag)
  const int hi   = lane >> 5;   // k-half selector

  const int qt = blockIdx.x & 31;   // 32 Q tiles of 128 rows
  const int h  = blockIdx.x >> 5;   // head

  __shared__ __bf16 Kl[SBLK][HDIM];   // K tile [s][d], swizzled
  __shared__ __bf16 Vt[HDIM][SBLK];   // V^T tile [d][s], swizzled

  // ---- Q as B-fragments: B[k=8*hi+e][col=lq] = Q[qrow(lq)][ds*16+8*hi+e] ----
  bf16x8 qf[4];
  const int qrow = qt * QBLK + wave * 32 + lq;
  {
    const float* qp = x + (size_t)qrow * DMODEL + h * HDIM;
    #pragma unroll
    for (int ds = 0; ds < 4; ds++) {
      float4 a = *reinterpret_cast<const float4*>(qp + ds * 16 + hi * 8);
      float4 b = *reinterpret_cast<const float4*>(qp + ds * 16 + hi * 8 + 4);
      bf16x8 f;
      f[0] = (__bf16)(QSCALE * a.x); f[1] = (__bf16)(QSCALE * a.y);
      f[2] = (__bf16)(QSCALE * a.z); f[3] = (__bf16)(QSCALE * a.w);
      f[4] = (__bf16)(QSCALE * b.x); f[5] = (__bf16)(QSCALE * b.y);
      f[6] = (__bf16)(QSCALE * b.z); f[7] = (__bf16)(QSCALE * b.w);
      qf[ds] = f;
    }
  }

  float m_run = -1e30f, l_run = 0.f;
  f32x16 oacc[2];   // O^T accumulators: col=q=lq, row=d pattern
  #pragma unroll
  for (int dt = 0; dt < 2; dt++)
    #pragma unroll
    for (int r = 0; r < 16; r++) oacc[dt][r] = 0.f;

  const float* xh = x + h * HDIM;
  const int c4 = tid & 15;   // staging col block (d/4)
  const int s4 = tid >> 4;   // staging row block (s/4)

  for (int t0 = 0; t0 < T_SEQ; t0 += SBLK) {
    __syncthreads();
    // ---- stage 64x64 f32 -> bf16 into Kl and Vt (4x4 micro-transpose) ----
    {
      const float* src = xh + (size_t)(t0 + s4 * 4) * DMODEL + c4 * 4;
      float4 r0 = *reinterpret_cast<const float4*>(src);
      float4 r1 = *reinterpret_cast<const float4*>(src + DMODEL);
      float4 r2 = *reinterpret_cast<const float4*>(src + 2 * DMODEL);
      float4 r3 = *reinterpret_cast<const float4*>(src + 3 * DMODEL);
      __bf16 b[4][4];
      b[0][0] = (__bf16)r0.x; b[0][1] = (__bf16)r0.y; b[0][2] = (__bf16)r0.z; b[0][3] = (__bf16)r0.w;
      b[1][0] = (__bf16)r1.x; b[1][1] = (__bf16)r1.y; b[1][2] = (__bf16)r1.z; b[1][3] = (__bf16)r1.w;
      b[2][0] = (__bf16)r2.x; b[2][1] = (__bf16)r2.y; b[2][2] = (__bf16)r2.z; b[2][3] = (__bf16)r2.w;
      b[3][0] = (__bf16)r3.x; b[3][1] = (__bf16)r3.y; b[3][2] = (__bf16)r3.z; b[3][3] = (__bf16)r3.w;
      #pragma unroll
      for (int j = 0; j < 4; j++) {
        const int s = s4 * 4 + j;
        bf16x4 kv; kv[0] = b[j][0]; kv[1] = b[j][1]; kv[2] = b[j][2]; kv[3] = b[j][3];
        *reinterpret_cast<bf16x4*>(&Kl[s][SWZ(s, c4 * 4)]) = kv;
      }
      #pragma unroll
      for (int i = 0; i < 4; i++) {
        const int d = c4 * 4 + i;
        bf16x4 vv; vv[0] = b[0][i]; vv[1] = b[1][i]; vv[2] = b[2][i]; vv[3] = b[3][i];
        *reinterpret_cast<bf16x4*>(&Vt[d][SWZ(d, s4 * 4)]) = vv;
      }
    }
    __syncthreads();

    // ---- S^T[k][q] = K·Q^T : 2 k-tiles x 4 d-slices of 32x32x16 ----
    f32x16 sacc[2];
    #pragma unroll
    for (int kt = 0; kt < 2; kt++)
      #pragma unroll
      for (int r = 0; r < 16; r++) sacc[kt][r] = 0.f;
    #pragma unroll
    for (int kt = 0; kt < 2; kt++) {
      #pragma unroll
      for (int ds = 0; ds < 4; ds++) {
        bf16x8 kb = *reinterpret_cast<const bf16x8*>(
            &Kl[kt * 32 + lq][SWZ(lq, ds * 16 + hi * 8)]);
        sacc[kt] = __builtin_amdgcn_mfma_f32_32x32x16_bf16(
            kb, qf[ds], sacc[kt], 0, 0, 0);
      }
    }

    // ---- in-register online softmax (exp2 domain) ----
    // lane holds S[q=lq][k = kt*32 + (reg&3)+8*(reg>>2)+4*hi];
    // partner lane^32 holds the complementary k-half.
    float mx = sacc[0][0];
    #pragma unroll
    for (int kt = 0; kt < 2; kt++)
      #pragma unroll
      for (int r = 0; r < 16; r++) mx = fmaxf(mx, sacc[kt][r]);
    mx = xhalf_max(mx);

    const float mn = fmaxf(m_run, mx);
    const float corr = __builtin_amdgcn_exp2f(m_run - mn);   // 0 on first tile
    #pragma unroll
    for (int dt = 0; dt < 2; dt++)
      #pragma unroll
      for (int r = 0; r < 16; r++) oacc[dt][r] *= corr;
    l_run *= corr;
    m_run = mn;

    float rs = 0.f;
    #pragma unroll
    for (int kt = 0; kt < 2; kt++)
      #pragma unroll
      for (int r = 0; r < 16; r++) {
        float p = __builtin_amdgcn_exp2f(sacc[kt][r] - mn);
        sacc[kt][r] = p;
        rs += p;
      }
    l_run += xhalf_sum(rs);

    // ---- P -> PV B-fragments (T12): swap(dA_i, dB_i), use BOTH outputs ----
    // Regs (per kt): hi=0 lane: regs 0-7 = k{0..3,8..11}; hi=1: k{4..7,12..15}.
    // dA_i = pk(regs base+2i, base+2i+1), dB_i = pk(regs base+4+2i, base+5+2i).
    // swap(dA_i, dB_i): dA_i[32:63] <- dB_i[0:31] (partner dB: k8.. for hi=1),
    //                   dB_i[0:31] <- dA_i[32:63] (partner dA: k4.. for hi=0).
    // Result u = {dA0', dA1', dB0', dB1'}:
    //   hi=0: {k0k1, k2k3, k4k5, k6k7}; hi=1: {k8k9, k10k11, k12k13, k14k15}.
    bf16x8 pf[4];
    #pragma unroll
    for (int kt = 0; kt < 2; kt++) {
      #pragma unroll
      for (int b2 = 0; b2 < 2; b2++) {
        const int base = 8 * b2;
        unsigned dA0 = cvt_pk_bf16(sacc[kt][base + 0], sacc[kt][base + 1]);
        unsigned dA1 = cvt_pk_bf16(sacc[kt][base + 2], sacc[kt][base + 3]);
        unsigned dB0 = cvt_pk_bf16(sacc[kt][base + 4], sacc[kt][base + 5]);
        unsigned dB1 = cvt_pk_bf16(sacc[kt][base + 6], sacc[kt][base + 7]);
        uint32x2 r0 = plswap(dA0, dB0);
        uint32x2 r1 = plswap(dA1, dB1);
        uint4 u; u.x = r0[0]; u.y = r1[0]; u.z = r0[1]; u.w = r1[1];
        pf[kt * 2 + b2] = *reinterpret_cast<bf16x8*>(&u);
      }
    }

    // ---- O^T += V^T · P^T : 2 d-tiles x 4 k-slices ----
    #pragma unroll
    for (int dt = 0; dt < 2; dt++) {
      #pragma unroll
      for (int ks = 0; ks < 4; ks++) {
        bf16x8 vb = *reinterpret_cast<const bf16x8*>(
            &Vt[dt * 32 + lq][SWZ(lq, ks * 16 + hi * 8)]);
        oacc[dt] = __builtin_amdgcn_mfma_f32_32x32x16_bf16(
            vb, pf[ks], oacc[dt], 0, 0, 0);
      }
    }
  }

  // ---- epilogue: lane owns q-row lq's O^T column; d = dt*32+8m+4hi+j ----
  const float inv = 1.f / l_run;
  float* orow = out + (size_t)qrow * DMODEL + h * HDIM;
  #pragma unroll
  for (int dt = 0; dt < 2; dt++) {
    #pragma unroll
    for (int m = 0; m < 4; m++) {
      float4 o;
      o.x = oacc[dt][4 * m + 0] * inv;
      o.y = oacc[dt][4 * m + 1] * inv;
      o.z = oacc[dt][4 * m + 2] * inv;
      o.w = oacc[dt][4 * m + 3] * inv;
      *reinterpret_cast<float4*>(&orow[dt * 32 + 8 * m + 4 * hi]) = o;
    }
  }
}

extern "C" void kernel_launch(void* const* d_in, const int* in_sizes, int n_in,
                              void* d_out, int out_size, void* d_ws, size_t ws_size,
                              hipStream_t stream) {
  const float* x = (const float*)d_in[0];
  float* out = (float*)d_out;
  dim3 grid(NHEADS * (T_SEQ / QBLK));   // 512 blocks
  attn_fused_kernel<<<grid, 256, 0, stream>>>(x, out);
}

// Round 6
// 162.277 us; speedup vs baseline: 2.3728x; 1.2112x over previous
//
#include <hip/hip_runtime.h>
#include <hip/hip_bf16.h>

#define T_SEQ 4096
#define DMODEL 1024
#define NHEADS 16
#define HDIM 64
#define QBLK 128   // 4 waves x 32 q-rows
#define SBLK 64    // KV rows per tile
#define NTILES (T_SEQ / SBLK)            // 64
#define KSPLIT 2
#define TILES_PER_SPLIT (NTILES / KSPLIT) // 32

// ---- workspace layout (bytes) ----
#define KV_BYTES ((size_t)NHEADS * NTILES * 16384)          // 16.78 MB bf16 images
#define OFF_P    KV_BYTES
#define P_BYTES  ((size_t)KSPLIT * T_SEQ * DMODEL * 4)      // 33.55 MB partial O
#define OFF_ML   (OFF_P + P_BYTES)
#define ML_BYTES ((size_t)KSPLIT * NHEADS * T_SEQ * 8)      // 1.05 MB (m,l)
#define WS_NEEDED (OFF_ML + ML_BYTES)

typedef __attribute__((ext_vector_type(8))) __bf16 bf16x8;
typedef __attribute__((ext_vector_type(4))) __bf16 bf16x4;
typedef __attribute__((ext_vector_type(16))) float f32x16;
typedef __attribute__((ext_vector_type(2))) unsigned uint32x2;

// XOR swizzle on the 8-element (16B) granule; row stride 128B.
#define SWZ(row, col) ((col) ^ (((row) & 7) << 3))

// 1/sqrt(64) * log2(e): softmax in exp2 domain.
#define QSCALE 0.1803368801111204f
#define DEFER_THR 8.0f

__device__ __forceinline__ unsigned cvt_pk_bf16(float lo, float hi) {
  unsigned r;
  asm("v_cvt_pk_bf16_f32 %0, %1, %2" : "=v"(r) : "v"(lo), "v"(hi));
  return r;
}
__device__ __forceinline__ uint32x2 plswap(unsigned a, unsigned b) {
  return __builtin_amdgcn_permlane32_swap(a, b, false, false);
}
__device__ __forceinline__ float xhalf_max(float v) {
  uint32x2 r = plswap(__float_as_uint(v), __float_as_uint(v));
  return fmaxf(__uint_as_float(r[0]), __uint_as_float(r[1]));
}
__device__ __forceinline__ float xhalf_sum(float v) {
  uint32x2 r = plswap(__float_as_uint(v), __float_as_uint(v));
  return __uint_as_float(r[0]) + __uint_as_float(r[1]);
}
__device__ __forceinline__ void glds16(const void* g, void* l) {
  __builtin_amdgcn_global_load_lds(
      (const __attribute__((address_space(1))) unsigned int*)g,
      (__attribute__((address_space(3))) unsigned int*)l, 16, 0, 0);
}

// ============ pre-pass: x (f32) -> pre-swizzled bf16 K/V^T tile images =====
// Image for (h,t): 8KB K part: [s][SWZ(s,d)] = x[t*64+s][h*64+d];
//                  8KB V part: [d][SWZ(d,s)] = x[t*64+s][h*64+d].
__global__ __launch_bounds__(256) void prepass_kernel(
    const float* __restrict__ x, unsigned char* __restrict__ kvimg) {
  const int tid = threadIdx.x;
  const int c4 = tid & 15, s4 = tid >> 4;
  const int t = blockIdx.x & (NTILES - 1), h = blockIdx.x >> 6;
  const float* src = x + (size_t)(t * SBLK + s4 * 4) * DMODEL + h * HDIM + c4 * 4;
  float4 r0 = *reinterpret_cast<const float4*>(src);
  float4 r1 = *reinterpret_cast<const float4*>(src + DMODEL);
  float4 r2 = *reinterpret_cast<const float4*>(src + 2 * DMODEL);
  float4 r3 = *reinterpret_cast<const float4*>(src + 3 * DMODEL);
  __bf16 b[4][4];
  b[0][0] = (__bf16)r0.x; b[0][1] = (__bf16)r0.y; b[0][2] = (__bf16)r0.z; b[0][3] = (__bf16)r0.w;
  b[1][0] = (__bf16)r1.x; b[1][1] = (__bf16)r1.y; b[1][2] = (__bf16)r1.z; b[1][3] = (__bf16)r1.w;
  b[2][0] = (__bf16)r2.x; b[2][1] = (__bf16)r2.y; b[2][2] = (__bf16)r2.z; b[2][3] = (__bf16)r2.w;
  b[3][0] = (__bf16)r3.x; b[3][1] = (__bf16)r3.y; b[3][2] = (__bf16)r3.z; b[3][3] = (__bf16)r3.w;
  __bf16* Kimg = (__bf16*)(kvimg + (size_t)blockIdx.x * 16384);
  __bf16* Vimg = Kimg + 4096;
  #pragma unroll
  for (int j = 0; j < 4; j++) {
    const int s = s4 * 4 + j;
    bf16x4 kv; kv[0] = b[j][0]; kv[1] = b[j][1]; kv[2] = b[j][2]; kv[3] = b[j][3];
    *reinterpret_cast<bf16x4*>(&Kimg[s * 64 + SWZ(s, c4 * 4)]) = kv;
  }
  #pragma unroll
  for (int i = 0; i < 4; i++) {
    const int d = c4 * 4 + i;
    bf16x4 vv; vv[0] = b[0][i]; vv[1] = b[1][i]; vv[2] = b[2][i]; vv[3] = b[3][i];
    *reinterpret_cast<bf16x4*>(&Vimg[d * 64 + SWZ(d, s4 * 4)]) = vv;
  }
}

// ============ main flash kernel (templated: split-KV or single-pass) =======
template <bool SPLIT>
__global__ __launch_bounds__(256, 4) void attn_main_kernel(
    const float* __restrict__ x, const unsigned char* __restrict__ kvimg,
    float* __restrict__ outbuf, float2* __restrict__ mlbuf) {
  const int tid  = threadIdx.x;
  const int wave = tid >> 6;
  const int lane = tid & 63;
  const int lq   = lane & 31;
  const int hi   = lane >> 5;

  const int qt = blockIdx.x & 31;
  const int h  = blockIdx.x >> 5;
  const int sp = SPLIT ? blockIdx.y : 0;
  const int ntiles = SPLIT ? TILES_PER_SPLIT : NTILES;

  __shared__ __align__(16) unsigned char kvbytes[2][16384];

  // ---- Q as B-fragments ----
  bf16x8 qf[4];
  const int qrow = qt * QBLK + wave * 32 + lq;
  {
    const float* qp = x + (size_t)qrow * DMODEL + h * HDIM;
    #pragma unroll
    for (int ds = 0; ds < 4; ds++) {
      float4 a = *reinterpret_cast<const float4*>(qp + ds * 16 + hi * 8);
      float4 b = *reinterpret_cast<const float4*>(qp + ds * 16 + hi * 8 + 4);
      bf16x8 f;
      f[0] = (__bf16)(QSCALE * a.x); f[1] = (__bf16)(QSCALE * a.y);
      f[2] = (__bf16)(QSCALE * a.z); f[3] = (__bf16)(QSCALE * a.w);
      f[4] = (__bf16)(QSCALE * b.x); f[5] = (__bf16)(QSCALE * b.y);
      f[6] = (__bf16)(QSCALE * b.z); f[7] = (__bf16)(QSCALE * b.w);
      qf[ds] = f;
    }
  }

  float m_run = -1e30f, l_run = 0.f;
  f32x16 oacc[2];
  #pragma unroll
  for (int dt = 0; dt < 2; dt++)
    #pragma unroll
    for (int r = 0; r < 16; r++) oacc[dt][r] = 0.f;

  const unsigned char* tbase =
      kvimg + ((size_t)(h * NTILES + sp * TILES_PER_SPLIT) * 16384);

  auto STAGE = [&](int buf, int t) {
    const unsigned char* g = tbase + (size_t)t * 16384;
    #pragma unroll
    for (int i = 0; i < 4; i++)
      glds16(g + i * 4096 + tid * 16, &kvbytes[buf][i * 4096 + tid * 16]);
  };

  STAGE(0, 0);
  __syncthreads();   // drains vmcnt(0): buf0 ready
  int cur = 0;

  for (int t = 0; t < ntiles; t++) {
    if (t + 1 < ntiles) STAGE(cur ^ 1, t + 1);   // prefetch overlaps compute
    const __bf16 (*Kl)[64] = reinterpret_cast<const __bf16(*)[64]>(&kvbytes[cur][0]);
    const __bf16 (*Vt)[64] = reinterpret_cast<const __bf16(*)[64]>(&kvbytes[cur][8192]);

    // ---- S^T = K·Q^T ----
    f32x16 sacc[2];
    #pragma unroll
    for (int kt = 0; kt < 2; kt++)
      #pragma unroll
      for (int r = 0; r < 16; r++) sacc[kt][r] = 0.f;
    #pragma unroll
    for (int kt = 0; kt < 2; kt++) {
      #pragma unroll
      for (int ds = 0; ds < 4; ds++) {
        bf16x8 kb = *reinterpret_cast<const bf16x8*>(
            &Kl[kt * 32 + lq][SWZ(lq, ds * 16 + hi * 8)]);
        sacc[kt] = __builtin_amdgcn_mfma_f32_32x32x16_bf16(
            kb, qf[ds], sacc[kt], 0, 0, 0);
      }
    }

    // ---- in-register online softmax (exp2 domain), defer-max ----
    float mx = sacc[0][0];
    #pragma unroll
    for (int kt = 0; kt < 2; kt++)
      #pragma unroll
      for (int r = 0; r < 16; r++) mx = fmaxf(mx, sacc[kt][r]);
    mx = xhalf_max(mx);

    float mn = m_run;
    if (!__all(mx <= m_run + DEFER_THR)) {
      mn = fmaxf(m_run, mx);
      const float corr = __builtin_amdgcn_exp2f(m_run - mn);
      #pragma unroll
      for (int dt = 0; dt < 2; dt++)
        #pragma unroll
        for (int r = 0; r < 16; r++) oacc[dt][r] *= corr;
      l_run *= corr;
      m_run = mn;
    }

    float rs = 0.f;
    #pragma unroll
    for (int kt = 0; kt < 2; kt++)
      #pragma unroll
      for (int r = 0; r < 16; r++) {
        float p = __builtin_amdgcn_exp2f(sacc[kt][r] - mn);
        sacc[kt][r] = p;
        rs += p;
      }
    l_run += xhalf_sum(rs);

    // ---- P -> PV B-fragments (T12: swap(dA,dB), both outputs used) ----
    bf16x8 pf[4];
    #pragma unroll
    for (int kt = 0; kt < 2; kt++) {
      #pragma unroll
      for (int b2 = 0; b2 < 2; b2++) {
        const int base = 8 * b2;
        unsigned dA0 = cvt_pk_bf16(sacc[kt][base + 0], sacc[kt][base + 1]);
        unsigned dA1 = cvt_pk_bf16(sacc[kt][base + 2], sacc[kt][base + 3]);
        unsigned dB0 = cvt_pk_bf16(sacc[kt][base + 4], sacc[kt][base + 5]);
        unsigned dB1 = cvt_pk_bf16(sacc[kt][base + 6], sacc[kt][base + 7]);
        uint32x2 r0 = plswap(dA0, dB0);
        uint32x2 r1 = plswap(dA1, dB1);
        uint4 u; u.x = r0[0]; u.y = r1[0]; u.z = r0[1]; u.w = r1[1];
        pf[kt * 2 + b2] = *reinterpret_cast<bf16x8*>(&u);
      }
    }

    // ---- O^T += V^T · P^T ----
    #pragma unroll
    for (int dt = 0; dt < 2; dt++) {
      #pragma unroll
      for (int ks = 0; ks < 4; ks++) {
        bf16x8 vb = *reinterpret_cast<const bf16x8*>(
            &Vt[dt * 32 + lq][SWZ(lq, ks * 16 + hi * 8)]);
        oacc[dt] = __builtin_amdgcn_mfma_f32_32x32x16_bf16(
            vb, pf[ks], oacc[dt], 0, 0, 0);
      }
    }

    __syncthreads();   // drains prefetch vmcnt + releases buf for overwrite
    cur ^= 1;
  }

  // ---- epilogue ----
  if (SPLIT) {
    float* prow = outbuf + (size_t)sp * T_SEQ * DMODEL +
                  (size_t)qrow * DMODEL + h * HDIM;
    #pragma unroll
    for (int dt = 0; dt < 2; dt++) {
      #pragma unroll
      for (int m = 0; m < 4; m++) {
        float4 o;
        o.x = oacc[dt][4 * m + 0]; o.y = oacc[dt][4 * m + 1];
        o.z = oacc[dt][4 * m + 2]; o.w = oacc[dt][4 * m + 3];
        *reinterpret_cast<float4*>(&prow[dt * 32 + 8 * m + 4 * hi]) = o;
      }
    }
    if (hi == 0)
      mlbuf[(size_t)(sp * NHEADS + h) * T_SEQ + qrow] = make_float2(m_run, l_run);
  } else {
    const float inv = 1.f / l_run;
    float* orow = outbuf + (size_t)qrow * DMODEL + h * HDIM;
    #pragma unroll
    for (int dt = 0; dt < 2; dt++) {
      #pragma unroll
      for (int m = 0; m < 4; m++) {
        float4 o;
        o.x = oacc[dt][4 * m + 0] * inv; o.y = oacc[dt][4 * m + 1] * inv;
        o.z = oacc[dt][4 * m + 2] * inv; o.w = oacc[dt][4 * m + 3] * inv;
        *reinterpret_cast<float4*>(&orow[dt * 32 + 8 * m + 4 * hi]) = o;
      }
    }
  }
}

// ============ merge: combine the 2 KV-split partials ======================
__global__ __launch_bounds__(256) void merge_kernel(
    const float* __restrict__ pbuf, const float2* __restrict__ mlbuf,
    float* __restrict__ out) {
  const int gid = blockIdx.x * 256 + threadIdx.x;   // float4 index
  const int row = gid >> 8;
  const int h = (gid & 255) >> 4;
  float2 ml0 = mlbuf[(size_t)h * T_SEQ + row];
  float2 ml1 = mlbuf[(size_t)(NHEADS + h) * T_SEQ + row];
  const float m = fmaxf(ml0.x, ml1.x);
  const float w0 = __builtin_amdgcn_exp2f(ml0.x - m);
  const float w1 = __builtin_amdgcn_exp2f(ml1.x - m);
  const float invL = 1.f / (ml0.y * w0 + ml1.y * w1);
  const float4 p0 = reinterpret_cast<const float4*>(pbuf)[gid];
  const float4 p1 = reinterpret_cast<const float4*>(pbuf)[(size_t)T_SEQ * DMODEL / 4 + gid];
  float4 o;
  o.x = (p0.x * w0 + p1.x * w1) * invL;
  o.y = (p0.y * w0 + p1.y * w1) * invL;
  o.z = (p0.z * w0 + p1.z * w1) * invL;
  o.w = (p0.w * w0 + p1.w * w1) * invL;
  reinterpret_cast<float4*>(out)[gid] = o;
}

// ============ fallback (round-5 green kernel, used if ws too small) ========
__global__ __launch_bounds__(256) void attn_fallback_kernel(
    const float* __restrict__ x, float* __restrict__ out) {
  const int tid  = threadIdx.x;
  const int wave = tid >> 6;
  const int lane = tid & 63;
  const int lq   = lane & 31;
  const int hi   = lane >> 5;
  const int qt = blockIdx.x & 31;
  const int h  = blockIdx.x >> 5;
  __shared__ __bf16 Kl[SBLK][HDIM];
  __shared__ __bf16 Vt[HDIM][SBLK];
  bf16x8 qf[4];
  const int qrow = qt * QBLK + wave * 32 + lq;
  {
    const float* qp = x + (size_t)qrow * DMODEL + h * HDIM;
    #pragma unroll
    for (int ds = 0; ds < 4; ds++) {
      float4 a = *reinterpret_cast<const float4*>(qp + ds * 16 + hi * 8);
      float4 b = *reinterpret_cast<const float4*>(qp + ds * 16 + hi * 8 + 4);
      bf16x8 f;
      f[0] = (__bf16)(QSCALE * a.x); f[1] = (__bf16)(QSCALE * a.y);
      f[2] = (__bf16)(QSCALE * a.z); f[3] = (__bf16)(QSCALE * a.w);
      f[4] = (__bf16)(QSCALE * b.x); f[5] = (__bf16)(QSCALE * b.y);
      f[6] = (__bf16)(QSCALE * b.z); f[7] = (__bf16)(QSCALE * b.w);
      qf[ds] = f;
    }
  }
  float m_run = -1e30f, l_run = 0.f;
  f32x16 oacc[2];
  #pragma unroll
  for (int dt = 0; dt < 2; dt++)
    #pragma unroll
    for (int r = 0; r < 16; r++) oacc[dt][r] = 0.f;
  const float* xh = x + h * HDIM;
  const int c4 = tid & 15;
  const int s4 = tid >> 4;
  for (int t0 = 0; t0 < T_SEQ; t0 += SBLK) {
    __syncthreads();
    {
      const float* src = xh + (size_t)(t0 + s4 * 4) * DMODEL + c4 * 4;
      float4 r0 = *reinterpret_cast<const float4*>(src);
      float4 r1 = *reinterpret_cast<const float4*>(src + DMODEL);
      float4 r2 = *reinterpret_cast<const float4*>(src + 2 * DMODEL);
      float4 r3 = *reinterpret_cast<const float4*>(src + 3 * DMODEL);
      __bf16 b[4][4];
      b[0][0] = (__bf16)r0.x; b[0][1] = (__bf16)r0.y; b[0][2] = (__bf16)r0.z; b[0][3] = (__bf16)r0.w;
      b[1][0] = (__bf16)r1.x; b[1][1] = (__bf16)r1.y; b[1][2] = (__bf16)r1.z; b[1][3] = (__bf16)r1.w;
      b[2][0] = (__bf16)r2.x; b[2][1] = (__bf16)r2.y; b[2][2] = (__bf16)r2.z; b[2][3] = (__bf16)r2.w;
      b[3][0] = (__bf16)r3.x; b[3][1] = (__bf16)r3.y; b[3][2] = (__bf16)r3.z; b[3][3] = (__bf16)r3.w;
      #pragma unroll
      for (int j = 0; j < 4; j++) {
        const int s = s4 * 4 + j;
        bf16x4 kv; kv[0] = b[j][0]; kv[1] = b[j][1]; kv[2] = b[j][2]; kv[3] = b[j][3];
        *reinterpret_cast<bf16x4*>(&Kl[s][SWZ(s, c4 * 4)]) = kv;
      }
      #pragma unroll
      for (int i = 0; i < 4; i++) {
        const int d = c4 * 4 + i;
        bf16x4 vv; vv[0] = b[0][i]; vv[1] = b[1][i]; vv[2] = b[2][i]; vv[3] = b[3][i];
        *reinterpret_cast<bf16x4*>(&Vt[d][SWZ(d, s4 * 4)]) = vv;
      }
    }
    __syncthreads();
    f32x16 sacc[2];
    #pragma unroll
    for (int kt = 0; kt < 2; kt++)
      #pragma unroll
      for (int r = 0; r < 16; r++) sacc[kt][r] = 0.f;
    #pragma unroll
    for (int kt = 0; kt < 2; kt++) {
      #pragma unroll
      for (int ds = 0; ds < 4; ds++) {
        bf16x8 kb = *reinterpret_cast<const bf16x8*>(
            &Kl[kt * 32 + lq][SWZ(lq, ds * 16 + hi * 8)]);
        sacc[kt] = __builtin_amdgcn_mfma_f32_32x32x16_bf16(
            kb, qf[ds], sacc[kt], 0, 0, 0);
      }
    }
    float mx = sacc[0][0];
    #pragma unroll
    for (int kt = 0; kt < 2; kt++)
      #pragma unroll
      for (int r = 0; r < 16; r++) mx = fmaxf(mx, sacc[kt][r]);
    mx = xhalf_max(mx);
    const float mn = fmaxf(m_run, mx);
    const float corr = __builtin_amdgcn_exp2f(m_run - mn);
    #pragma unroll
    for (int dt = 0; dt < 2; dt++)
      #pragma unroll
      for (int r = 0; r < 16; r++) oacc[dt][r] *= corr;
    l_run *= corr;
    m_run = mn;
    float rs = 0.f;
    #pragma unroll
    for (int kt = 0; kt < 2; kt++)
      #pragma unroll
      for (int r = 0; r < 16; r++) {
        float p = __builtin_amdgcn_exp2f(sacc[kt][r] - mn);
        sacc[kt][r] = p;
        rs += p;
      }
    l_run += xhalf_sum(rs);
    bf16x8 pf[4];
    #pragma unroll
    for (int kt = 0; kt < 2; kt++) {
      #pragma unroll
      for (int b2 = 0; b2 < 2; b2++) {
        const int base = 8 * b2;
        unsigned dA0 = cvt_pk_bf16(sacc[kt][base + 0], sacc[kt][base + 1]);
        unsigned dA1 = cvt_pk_bf16(sacc[kt][base + 2], sacc[kt][base + 3]);
        unsigned dB0 = cvt_pk_bf16(sacc[kt][base + 4], sacc[kt][base + 5]);
        unsigned dB1 = cvt_pk_bf16(sacc[kt][base + 6], sacc[kt][base + 7]);
        uint32x2 r0 = plswap(dA0, dB0);
        uint32x2 r1 = plswap(dA1, dB1);
        uint4 u; u.x = r0[0]; u.y = r1[0]; u.z = r0[1]; u.w = r1[1];
        pf[kt * 2 + b2] = *reinterpret_cast<bf16x8*>(&u);
      }
    }
    #pragma unroll
    for (int dt = 0; dt < 2; dt++) {
      #pragma unroll
      for (int ks = 0; ks < 4; ks++) {
        bf16x8 vb = *reinterpret_cast<const bf16x8*>(
            &Vt[dt * 32 + lq][SWZ(lq, ks * 16 + hi * 8)]);
        oacc[dt] = __builtin_amdgcn_mfma_f32_32x32x16_bf16(
            vb, pf[ks], oacc[dt], 0, 0, 0);
      }
    }
  }
  const float inv = 1.f / l_run;
  float* orow = out + (size_t)qrow * DMODEL + h * HDIM;
  #pragma unroll
  for (int dt = 0; dt < 2; dt++) {
    #pragma unroll
    for (int m = 0; m < 4; m++) {
      float4 o;
      o.x = oacc[dt][4 * m + 0] * inv; o.y = oacc[dt][4 * m + 1] * inv;
      o.z = oacc[dt][4 * m + 2] * inv; o.w = oacc[dt][4 * m + 3] * inv;
      *reinterpret_cast<float4*>(&orow[dt * 32 + 8 * m + 4 * hi]) = o;
    }
  }
}

extern "C" void kernel_launch(void* const* d_in, const int* in_sizes, int n_in,
                              void* d_out, int out_size, void* d_ws, size_t ws_size,
                              hipStream_t stream) {
  const float* x = (const float*)d_in[0];
  float* out = (float*)d_out;
  if (ws_size >= WS_NEEDED) {
    unsigned char* kvimg = (unsigned char*)d_ws;
    float* pbuf = (float*)((unsigned char*)d_ws + OFF_P);
    float2* mlbuf = (float2*)((unsigned char*)d_ws + OFF_ML);
    prepass_kernel<<<NHEADS * NTILES, 256, 0, stream>>>(x, kvimg);
    dim3 grid(NHEADS * (T_SEQ / QBLK), KSPLIT);   // 512 x 2
    attn_main_kernel<true><<<grid, 256, 0, stream>>>(x, kvimg, pbuf, mlbuf);
    merge_kernel<<<T_SEQ * DMODEL / 4 / 256, 256, 0, stream>>>(pbuf, mlbuf, out);
  } else if (ws_size >= KV_BYTES) {
    unsigned char* kvimg = (unsigned char*)d_ws;
    prepass_kernel<<<NHEADS * NTILES, 256, 0, stream>>>(x, kvimg);
    dim3 grid(NHEADS * (T_SEQ / QBLK), 1);
    attn_main_kernel<false><<<grid, 256, 0, stream>>>(x, kvimg, out, nullptr);
  } else {
    attn_fallback_kernel<<<NHEADS * (T_SEQ / QBLK), 256, 0, stream>>>(x, out);
  }
}